// Round 5
// baseline (382.661 us; speedup 1.0000x reference)
//
#include <hip/hip_runtime.h>
#include <math.h>

#define N_NODES 50000
#define N_EDGES 800000
#define NFEAT   512
#define NHID    64
#define NCLASS  40
#define SLOTS   64   // bucket capacity: deg ~ Poisson(16), P(deg>64) ~ 1e-19

#define GEMM_BLOCKS (N_NODES / 16)   // 3125 (16 rows/block, 4 waves = 4 col-tiles)
#define SCAT_BLOCKS (N_EDGES / 256)  // 3125 (256 edges/block)

typedef __attribute__((ext_vector_type(8))) short bf16x8;   // 8 bf16 (4 VGPRs)
typedef __attribute__((ext_vector_type(4))) float f32x4;    // MFMA C/D

__device__ inline unsigned short f2bf(float f) {            // fp32 -> bf16 RNE
    unsigned int u = __float_as_uint(f);
    u += 0x7FFFu + ((u >> 16) & 1u);
    return (unsigned short)(u >> 16);
}
__device__ inline float bf2f(unsigned short u) {            // bf16 -> fp32
    return __uint_as_float(((unsigned int)u) << 16);
}

// ---------------------------------------------------------------------------
// Round 14: rounds 3+4 proved gemm1's 84us is wave-count-bound: 16 rows/wave
// fixes 3125 waves (~12/CU) regardless of block shape -> 1.33 TB/s. Fix:
// col-split — block = 16 rows, its 4 waves each compute ONE 16-col MFMA tile
// -> 12500 gemm waves (~4x concurrency); A-re-reads across waves hit L1/L2.
// Scatter blocks interleaved by parity to mix atomic + streaming waves.
// ---------------------------------------------------------------------------

__global__ void init_kernel(int* __restrict__ cursor,
                            const float* __restrict__ W1,
                            unsigned short* __restrict__ w1t) {
    int i = blockIdx.x * blockDim.x + threadIdx.x;
    if (i < N_NODES) cursor[i] = 0;
    if (i < NFEAT * NHID) {                      // W1 is [k][c], c fastest
        int k = i >> 6, c = i & 63;
        w1t[(size_t)c * NFEAT + k] = f2bf(W1[i]);
    }
}

// ---------------------------------------------------------------------------
// Fused GEMM1 + scatter, parity-interleaved. Even blocks: gemm (16 rows,
// wave wv = col-tile [wv*16, wv*16+16)). Odd blocks: bucket-scatter.
// Fragment maps (HW-verified m89/m120): A[m=lane&15][k=quad*8+j],
// B[k=quad*8+j][n=lane&15], D: col=lane&15, row=quad*4+reg.
// ---------------------------------------------------------------------------
__global__ __launch_bounds__(256) void gemm1_scatter_kernel(
        const float* __restrict__ x,
        const unsigned short* __restrict__ w1t,
        unsigned short* __restrict__ xw,
        const int* __restrict__ dst,
        const int* __restrict__ src,
        const float* __restrict__ adj_vals,
        int* __restrict__ cursor,
        unsigned int* __restrict__ ev2) {
    const int tid = threadIdx.x;
    const unsigned b = blockIdx.x;

    if (b & 1u) {                                // ---- scatter block ----
        const int i = (b >> 1) * 256 + tid;      // exact: 3125*256 = 800000
        const int d = dst[i];
        const int p = atomicAdd(&cursor[d], 1);
        if (p < SLOTS)   // insurance; statistically never taken
            ev2[(size_t)d * SLOTS + p] =
                (unsigned int)src[i] | ((unsigned int)f2bf(adj_vals[i]) << 16);
        return;
    }

    // ---- gemm block: 16 rows; wave wv computes col-tile wv ----
    const int gb   = b >> 1;                     // 0..3124
    const int lane = tid & 63;
    const int wv   = tid >> 6;
    const int i16  = lane & 15;
    const int quad = lane >> 4;

    const float* xrow = x + (size_t)(gb * 16 + i16) * NFEAT + quad * 8;  // exact
    const unsigned short* wb = w1t + (size_t)(wv * 16 + i16) * NFEAT + quad * 8;

    f32x4 acc = {0.f, 0.f, 0.f, 0.f};

    float4 pa[4], pb[4];      // A prefetch, 4 K-steps deep (8 loads in flight)
    bf16x8 bf[2];             // B prefetch, 2 deep (L1-resident)

#pragma unroll
    for (int s = 0; s < 4; ++s) {
        pa[s] = *reinterpret_cast<const float4*>(xrow + s * 32);
        pb[s] = *reinterpret_cast<const float4*>(xrow + s * 32 + 4);
    }
#pragma unroll
    for (int s = 0; s < 2; ++s)
        bf[s] = *reinterpret_cast<const bf16x8*>(wb + s * 32);

#pragma unroll
    for (int s = 0; s < 16; ++s) {               // fully unrolled: static idx
        float4 xa = pa[s & 3], xb = pb[s & 3];
        bf16x8 a;
        a[0] = (short)f2bf(xa.x); a[1] = (short)f2bf(xa.y);
        a[2] = (short)f2bf(xa.z); a[3] = (short)f2bf(xa.w);
        a[4] = (short)f2bf(xb.x); a[5] = (short)f2bf(xb.y);
        a[6] = (short)f2bf(xb.z); a[7] = (short)f2bf(xb.w);
        acc = __builtin_amdgcn_mfma_f32_16x16x32_bf16(a, bf[s & 1], acc, 0, 0, 0);
        if (s + 4 < 16) {
            pa[s & 3] = *reinterpret_cast<const float4*>(xrow + (s + 4) * 32);
            pb[s & 3] = *reinterpret_cast<const float4*>(xrow + (s + 4) * 32 + 4);
        }
        if (s + 2 < 16)
            bf[s & 1] = *reinterpret_cast<const bf16x8*>(wb + (s + 2) * 32);
    }

    // D: row = quad*4 + reg, col = wv*16 + i16
    unsigned short* op = xw + (size_t)(gb * 16 + quad * 4) * NHID + wv * 16 + i16;
#pragma unroll
    for (int reg = 0; reg < 4; ++reg)
        op[(size_t)reg * NHID] = f2bf(acc[reg]);
}

// ---------------------------------------------------------------------------
// Fused SpMM1 + bias + relu + GEMM2. Wave per row, lane = feature for the
// gather phase; h-row lands in LDS; then lanes 0..19 compute 2 classes each
// against LDS-staged W2 (fp32). hw rows padded to stride 64 (bf16): one
// aligned 128B line per row for spmm2's gathers.
// ---------------------------------------------------------------------------
__global__ __launch_bounds__(256) void spmm1_gemm2_kernel(
        const unsigned short* __restrict__ xw,
        const unsigned int* __restrict__ ev2,
        const int* __restrict__ counts,
        const float* __restrict__ b1,
        const float* __restrict__ W2,
        unsigned short* __restrict__ hw) {
    __shared__ float w2lds[NHID * NCLASS];       // 10.25 KB, layout == W2
    __shared__ float hlds[4][NHID];              // 1 KB
    const int tid  = threadIdx.x;
    const int lane = tid & 63;
    const int wv   = tid >> 6;

    for (int idx = tid; idx < NHID * NCLASS; idx += 256) w2lds[idx] = W2[idx];
    __syncthreads();

    const int row = blockIdx.x * 4 + wv;         // exact: 12500*4 = 50000
    int cnt = counts[row];
    if (cnt > SLOTS) cnt = SLOTS;
    const unsigned int* erow = ev2 + (size_t)row * SLOTS;

    float acc = 0.f;
    int i = 0;
    for (; i + 7 < cnt; i += 8) {
        unsigned int e[8];
#pragma unroll
        for (int j = 0; j < 8; ++j) e[j] = erow[i + j];
        unsigned short g[8];
#pragma unroll
        for (int j = 0; j < 8; ++j)
            g[j] = xw[(size_t)(e[j] & 0xFFFFu) * NHID + lane];
#pragma unroll
        for (int j = 0; j < 8; ++j)
            acc += __uint_as_float(e[j] & 0xFFFF0000u) * bf2f(g[j]);
    }
    for (; i < cnt; ++i) {
        unsigned int e = erow[i];
        acc += __uint_as_float(e & 0xFFFF0000u) * bf2f(xw[(size_t)(e & 0xFFFFu) * NHID + lane]);
    }

    hlds[wv][lane] = fmaxf(acc + b1[lane], 0.f); // h row, fp32 (never hits HBM)

    // gemm2 epilogue: wave-internal ds_write -> ds_read (in-order per wave)
    if (lane < 20) {
        const int c0 = lane * 2;
        float d0 = 0.f, d1 = 0.f;
#pragma unroll
        for (int k = 0; k < NHID; ++k) {
            float hv = hlds[wv][k];              // wave-uniform -> broadcast
            d0 = fmaf(hv, w2lds[k * NCLASS + c0],     d0);
            d1 = fmaf(hv, w2lds[k * NCLASS + c0 + 1], d1);
        }
        unsigned int pack = (unsigned int)f2bf(d0) | ((unsigned int)f2bf(d1) << 16);
        *reinterpret_cast<unsigned int*>(hw + (size_t)row * 64 + c0) = pack;
    }
}

// ---------------------------------------------------------------------------
// SpMM2 + b2 + log_softmax. Wave per row, lanes 0..39 = classes.
// ---------------------------------------------------------------------------
__global__ void spmm2_lsm_kernel(const unsigned short* __restrict__ hw,
                                 const unsigned int* __restrict__ ev2,
                                 const int* __restrict__ counts,
                                 const float* __restrict__ b2,
                                 float* __restrict__ out) {
    const int lane = threadIdx.x & 63;
    const int row  = blockIdx.x * 4 + (threadIdx.x >> 6);
    const bool active = lane < NCLASS;
    const int cl = active ? lane : (NCLASS - 1);
    int cnt = counts[row];
    if (cnt > SLOTS) cnt = SLOTS;
    const unsigned int* erow = ev2 + (size_t)row * SLOTS;
    float acc = 0.f;
    int i = 0;
    for (; i + 7 < cnt; i += 8) {
        unsigned int e[8];
#pragma unroll
        for (int j = 0; j < 8; ++j) e[j] = erow[i + j];
        unsigned short g[8];
#pragma unroll
        for (int j = 0; j < 8; ++j)
            g[j] = hw[(size_t)(e[j] & 0xFFFFu) * 64 + cl];
#pragma unroll
        for (int j = 0; j < 8; ++j)
            acc += __uint_as_float(e[j] & 0xFFFF0000u) * bf2f(g[j]);
    }
    for (; i < cnt; ++i) {
        unsigned int e = erow[i];
        acc += __uint_as_float(e & 0xFFFF0000u) * bf2f(hw[(size_t)(e & 0xFFFFu) * 64 + cl]);
    }

    float logit = acc + b2[cl];
    float m = active ? logit : -INFINITY;
#pragma unroll
    for (int o = 32; o > 0; o >>= 1) m = fmaxf(m, __shfl_xor(m, o));
    float ex = active ? expf(logit - m) : 0.f;
    float ssum = ex;
#pragma unroll
    for (int o = 32; o > 0; o >>= 1) ssum += __shfl_xor(ssum, o);
    if (active) out[(size_t)row * NCLASS + lane] = logit - m - logf(ssum);
}

// ---------------------------------------------------------------------------

extern "C" void kernel_launch(void* const* d_in, const int* in_sizes, int n_in,
                              void* d_out, int out_size, void* d_ws, size_t ws_size,
                              hipStream_t stream) {
    const float* x        = (const float*)d_in[0];
    const float* adj_vals = (const float*)d_in[1];
    const float* W1       = (const float*)d_in[2];
    const float* b1       = (const float*)d_in[3];
    const float* W2       = (const float*)d_in[4];
    const float* b2       = (const float*)d_in[5];
    const int*   src      = (const int*)d_in[6];
    const int*   dst      = (const int*)d_in[7];
    float* out = (float*)d_out;

    // Workspace layout (25.8 MB). w1t aliases hw's region: w1t is dead after
    // gemm1_scatter completes, hw written by the following kernel.
    const size_t OFF_HW   = 6400000;             // hw  : 50000*64 bf16 (6.4 MB)
    const size_t OFF_CUR  = 12800000;            // cursor/counts : 50000 int
    const size_t OFF_EV   = 13000000;            // ev2 : 50000*64 uint (12.8 MB)
    const size_t REQUIRED = OFF_EV + (size_t)N_NODES * SLOTS * 4;  // 25,800,000 B
    if (ws_size < REQUIRED) return;              // refuse to write OOB

    char* ws = (char*)d_ws;
    unsigned short* xw     = (unsigned short*)(ws);
    unsigned short* hw     = (unsigned short*)(ws + OFF_HW);
    unsigned short* w1t    = (unsigned short*)(ws + OFF_HW);  // dead before hw written
    int*            cursor = (int*)  (ws + OFF_CUR);
    unsigned int*   ev2    = (unsigned int*)(ws + OFF_EV);

    init_kernel<<<(N_NODES + 255) / 256, 256, 0, stream>>>(cursor, W1, w1t);
    gemm1_scatter_kernel<<<GEMM_BLOCKS + SCAT_BLOCKS, 256, 0, stream>>>(
        x, w1t, xw, dst, src, adj_vals, cursor, ev2);
    spmm1_gemm2_kernel<<<N_NODES / 4, 256, 0, stream>>>(xw, ev2, cursor, b1, W2, hw);
    spmm2_lsm_kernel<<<N_NODES / 4, 256, 0, stream>>>(hw, ev2, cursor, b2, out);
}

// Round 6
// 308.617 us; speedup vs baseline: 1.2399x; 1.2399x over previous
//
#include <hip/hip_runtime.h>
#include <math.h>

#define N_NODES 50000
#define N_EDGES 800000
#define NFEAT   512
#define NHID    64
#define NCLASS  40
#define SLOTS   64   // bucket capacity: deg ~ Poisson(16), P(deg>64) ~ 1e-19

#define GEMM_BLOCKS ((N_NODES + 63) / 64)  // 782  (4 waves x 16 rows)
#define SCAT_BLOCKS (N_EDGES / 256)        // 3125 (256 edges/block)

typedef __attribute__((ext_vector_type(8))) short bf16x8;   // 8 bf16 (4 VGPRs)
typedef __attribute__((ext_vector_type(4))) float f32x4;    // MFMA C/D

typedef __attribute__((address_space(1))) const void GVOID;
typedef __attribute__((address_space(3))) void LVOID;

__device__ inline unsigned short f2bf(float f) {            // fp32 -> bf16 RNE
    unsigned int u = __float_as_uint(f);
    u += 0x7FFFu + ((u >> 16) & 1u);
    return (unsigned short)(u >> 16);
}
__device__ inline float bf2f(unsigned short u) {            // bf16 -> fp32
    return __uint_as_float(((unsigned int)u) << 16);
}

// ---------------------------------------------------------------------------
// Round 15: rounds 3-5 proved register-prefetch gemm1 is latency-walled
// (~8 outstanding/wave x 12 waves/CU) and col-split re-reads regress. Fix per
// guide (m97): async global_load_lds staging, double-buffered, per-wave-
// private (no barriers), counted vmcnt(12/8) waits, XOR-swizzled LDS reads
// (swizzle applied on the GLOBAL source per m173; LDS dest stays linear).
// Scatter blocks appended after gemm blocks (round-4 ordering restored).
// ---------------------------------------------------------------------------

__global__ void init_kernel(int* __restrict__ cursor,
                            const float* __restrict__ W1,
                            unsigned short* __restrict__ w1t) {
    int i = blockIdx.x * blockDim.x + threadIdx.x;
    if (i < N_NODES) cursor[i] = 0;
    if (i < NFEAT * NHID) {                      // W1 is [k][c], c fastest
        int k = i >> 6, c = i & 63;
        w1t[(size_t)c * NFEAT + k] = f2bf(W1[i]);
    }
}

// ---------------------------------------------------------------------------
// Fused GEMM1 + scatter. Blocks [0,782): xw = x @ W1 (MFMA, bf16 out, one
// 128B line per row); wave = 16 rows x 64 cols, K=512 in 8 steps of 64.
// Blocks [782,782+3125): bucket-scatter edges.
// Fragment maps (HW-verified m89/m120): A[m=lane&15][k=quad*8+j],
// B[k=quad*8+j][n=lane&15], D: col=lane&15, row=quad*4+reg.
// ---------------------------------------------------------------------------
__global__ __launch_bounds__(256) void gemm1_scatter_kernel(
        const float* __restrict__ x,
        const unsigned short* __restrict__ w1t,
        unsigned short* __restrict__ xw,
        const int* __restrict__ dst,
        const int* __restrict__ src,
        const float* __restrict__ adj_vals,
        int* __restrict__ cursor,
        unsigned int* __restrict__ ev2) {
    __shared__ float lds[2][4][16][64];          // [buf][wave][row][slot*4] 32 KB
    const int tid = threadIdx.x;
    const unsigned b = blockIdx.x;

    if (b >= GEMM_BLOCKS) {                      // ---- scatter block ----
        const int i = (b - GEMM_BLOCKS) * 256 + tid;   // exact: 3125*256 = 800000
        const int d = dst[i];
        const int p = atomicAdd(&cursor[d], 1);
        if (p < SLOTS)   // insurance; statistically never taken
            ev2[(size_t)d * SLOTS + p] =
                (unsigned int)src[i] | ((unsigned int)f2bf(adj_vals[i]) << 16);
        return;
    }

    // ---- gemm block: 4 waves x 16 rows; async LDS-staged A ----
    const int lane = tid & 63;
    const int wv   = tid >> 6;
    const int i16  = lane & 15;
    const int quad = lane >> 4;
    const int lsub = lane >> 4;                  // row-in-4-group for staging
    const int slot = lane & 15;                  // 16B slot for staging

    const int row0 = b * 64 + wv * 16;

    // Per-lane pre-swizzled global source rows/cols for the 4 staging instrs.
    // LDS[lr][s] holds x[row][ (s ^ lr)*4 .. +4 ]  (lr = local row 0..15).
    const float* gsrc[4];
#pragma unroll
    for (int i = 0; i < 4; ++i) {
        const int lr = i * 4 + lsub;
        int r = row0 + lr;
        if (r > N_NODES - 1) r = N_NODES - 1;
        gsrc[i] = x + (size_t)r * NFEAT + ((slot ^ lr) << 2);
    }

    const unsigned short* wb = w1t + (size_t)i16 * NFEAT + (quad << 3);

    f32x4 acc[4];
#pragma unroll
    for (int ct = 0; ct < 4; ++ct) acc[ct] = (f32x4){0.f, 0.f, 0.f, 0.f};

    // prologue: stage K-step 0 into buf 0
#pragma unroll
    for (int i = 0; i < 4; ++i)
        __builtin_amdgcn_global_load_lds((GVOID*)(gsrc[i]),
            (LVOID*)&lds[0][wv][i * 4][0], 16, 0, 0);

#pragma unroll
    for (int t = 0; t < 8; ++t) {
        if (t < 7) {                             // stage K-step t+1 into buf^1
#pragma unroll
            for (int i = 0; i < 4; ++i)
                __builtin_amdgcn_global_load_lds((GVOID*)(gsrc[i] + (t + 1) * 64),
                    (LVOID*)&lds[(t + 1) & 1][wv][i * 4][0], 16, 0, 0);
        }
        // B fragments for this K-step (w1t is L1/L2-resident, 64 KB)
        bf16x8 bfr[4][2];
#pragma unroll
        for (int ct = 0; ct < 4; ++ct)
#pragma unroll
            for (int ks = 0; ks < 2; ++ks)
                bfr[ct][ks] = *reinterpret_cast<const bf16x8*>(
                    wb + (size_t)ct * 16 * NFEAT + t * 64 + ks * 32);

        // In this window exactly [4 stage(t+1) + 8 B] newer than stage(t):
        // vmcnt(12) => stage(t) landed, stage(t+1) still in flight.
        if (t < 7) asm volatile("s_waitcnt vmcnt(12)" ::: "memory");
        else       asm volatile("s_waitcnt vmcnt(8)"  ::: "memory");
        __builtin_amdgcn_sched_barrier(0);

        const float4* lrow = reinterpret_cast<const float4*>(&lds[t & 1][wv][i16][0]);
#pragma unroll
        for (int ks = 0; ks < 2; ++ks) {
            const int s0 = (ks * 8 + quad * 2) ^ i16;
            const int s1 = (ks * 8 + quad * 2 + 1) ^ i16;
            float4 fa = lrow[s0];
            float4 fb = lrow[s1];
            bf16x8 a;
            a[0] = (short)f2bf(fa.x); a[1] = (short)f2bf(fa.y);
            a[2] = (short)f2bf(fa.z); a[3] = (short)f2bf(fa.w);
            a[4] = (short)f2bf(fb.x); a[5] = (short)f2bf(fb.y);
            a[6] = (short)f2bf(fb.z); a[7] = (short)f2bf(fb.w);
#pragma unroll
            for (int ct = 0; ct < 4; ++ct)
                acc[ct] = __builtin_amdgcn_mfma_f32_16x16x32_bf16(a, bfr[ct][ks], acc[ct], 0, 0, 0);
        }
    }

    const int orow0 = row0 + quad * 4;
#pragma unroll
    for (int reg = 0; reg < 4; ++reg) {
        const int orow = orow0 + reg;
        if (orow < N_NODES) {
            unsigned short* op = xw + (size_t)orow * NHID + i16;
            op[ 0] = f2bf(acc[0][reg]);
            op[16] = f2bf(acc[1][reg]);
            op[32] = f2bf(acc[2][reg]);
            op[48] = f2bf(acc[3][reg]);
        }
    }
}

// ---------------------------------------------------------------------------
// Fused SpMM1 + bias + relu + GEMM2. Wave per row, lane = feature for the
// gather phase; h-row lands in LDS; then lanes 0..19 compute 2 classes each
// against LDS-staged W2 (fp32). hw rows padded to stride 64 (bf16): one
// aligned 128B line per row for spmm2's gathers.
// ---------------------------------------------------------------------------
__global__ __launch_bounds__(256) void spmm1_gemm2_kernel(
        const unsigned short* __restrict__ xw,
        const unsigned int* __restrict__ ev2,
        const int* __restrict__ counts,
        const float* __restrict__ b1,
        const float* __restrict__ W2,
        unsigned short* __restrict__ hw) {
    __shared__ float w2lds[NHID * NCLASS];       // 10.25 KB, layout == W2
    __shared__ float hlds[4][NHID];              // 1 KB
    const int tid  = threadIdx.x;
    const int lane = tid & 63;
    const int wv   = tid >> 6;

    for (int idx = tid; idx < NHID * NCLASS; idx += 256) w2lds[idx] = W2[idx];
    __syncthreads();

    const int row = blockIdx.x * 4 + wv;         // exact: 12500*4 = 50000
    int cnt = counts[row];
    if (cnt > SLOTS) cnt = SLOTS;
    const unsigned int* erow = ev2 + (size_t)row * SLOTS;

    float acc = 0.f;
    int i = 0;
    for (; i + 7 < cnt; i += 8) {
        unsigned int e[8];
#pragma unroll
        for (int j = 0; j < 8; ++j) e[j] = erow[i + j];
        unsigned short g[8];
#pragma unroll
        for (int j = 0; j < 8; ++j)
            g[j] = xw[(size_t)(e[j] & 0xFFFFu) * NHID + lane];
#pragma unroll
        for (int j = 0; j < 8; ++j)
            acc += __uint_as_float(e[j] & 0xFFFF0000u) * bf2f(g[j]);
    }
    for (; i < cnt; ++i) {
        unsigned int e = erow[i];
        acc += __uint_as_float(e & 0xFFFF0000u) * bf2f(xw[(size_t)(e & 0xFFFFu) * NHID + lane]);
    }

    hlds[wv][lane] = fmaxf(acc + b1[lane], 0.f); // h row, fp32 (never hits HBM)

    // gemm2 epilogue: wave-internal ds_write -> ds_read (in-order per wave)
    if (lane < 20) {
        const int c0 = lane * 2;
        float d0 = 0.f, d1 = 0.f;
#pragma unroll
        for (int k = 0; k < NHID; ++k) {
            float hv = hlds[wv][k];              // wave-uniform -> broadcast
            d0 = fmaf(hv, w2lds[k * NCLASS + c0],     d0);
            d1 = fmaf(hv, w2lds[k * NCLASS + c0 + 1], d1);
        }
        unsigned int pack = (unsigned int)f2bf(d0) | ((unsigned int)f2bf(d1) << 16);
        *reinterpret_cast<unsigned int*>(hw + (size_t)row * 64 + c0) = pack;
    }
}

// ---------------------------------------------------------------------------
// SpMM2 + b2 + log_softmax. Wave per row, lanes 0..39 = classes.
// ---------------------------------------------------------------------------
__global__ void spmm2_lsm_kernel(const unsigned short* __restrict__ hw,
                                 const unsigned int* __restrict__ ev2,
                                 const int* __restrict__ counts,
                                 const float* __restrict__ b2,
                                 float* __restrict__ out) {
    const int lane = threadIdx.x & 63;
    const int row  = blockIdx.x * 4 + (threadIdx.x >> 6);
    const bool active = lane < NCLASS;
    const int cl = active ? lane : (NCLASS - 1);
    int cnt = counts[row];
    if (cnt > SLOTS) cnt = SLOTS;
    const unsigned int* erow = ev2 + (size_t)row * SLOTS;
    float acc = 0.f;
    int i = 0;
    for (; i + 7 < cnt; i += 8) {
        unsigned int e[8];
#pragma unroll
        for (int j = 0; j < 8; ++j) e[j] = erow[i + j];
        unsigned short g[8];
#pragma unroll
        for (int j = 0; j < 8; ++j)
            g[j] = hw[(size_t)(e[j] & 0xFFFFu) * 64 + cl];
#pragma unroll
        for (int j = 0; j < 8; ++j)
            acc += __uint_as_float(e[j] & 0xFFFF0000u) * bf2f(g[j]);
    }
    for (; i < cnt; ++i) {
        unsigned int e = erow[i];
        acc += __uint_as_float(e & 0xFFFF0000u) * bf2f(hw[(size_t)(e & 0xFFFFu) * 64 + cl]);
    }

    float logit = acc + b2[cl];
    float m = active ? logit : -INFINITY;
#pragma unroll
    for (int o = 32; o > 0; o >>= 1) m = fmaxf(m, __shfl_xor(m, o));
    float ex = active ? expf(logit - m) : 0.f;
    float ssum = ex;
#pragma unroll
    for (int o = 32; o > 0; o >>= 1) ssum += __shfl_xor(ssum, o);
    if (active) out[(size_t)row * NCLASS + lane] = logit - m - logf(ssum);
}

// ---------------------------------------------------------------------------

extern "C" void kernel_launch(void* const* d_in, const int* in_sizes, int n_in,
                              void* d_out, int out_size, void* d_ws, size_t ws_size,
                              hipStream_t stream) {
    const float* x        = (const float*)d_in[0];
    const float* adj_vals = (const float*)d_in[1];
    const float* W1       = (const float*)d_in[2];
    const float* b1       = (const float*)d_in[3];
    const float* W2       = (const float*)d_in[4];
    const float* b2       = (const float*)d_in[5];
    const int*   src      = (const int*)d_in[6];
    const int*   dst      = (const int*)d_in[7];
    float* out = (float*)d_out;

    // Workspace layout (25.8 MB). w1t aliases hw's region: w1t is dead after
    // gemm1_scatter completes, hw written by the following kernel.
    const size_t OFF_HW   = 6400000;             // hw  : 50000*64 bf16 (6.4 MB)
    const size_t OFF_CUR  = 12800000;            // cursor/counts : 50000 int
    const size_t OFF_EV   = 13000000;            // ev2 : 50000*64 uint (12.8 MB)
    const size_t REQUIRED = OFF_EV + (size_t)N_NODES * SLOTS * 4;  // 25,800,000 B
    if (ws_size < REQUIRED) return;              // refuse to write OOB

    char* ws = (char*)d_ws;
    unsigned short* xw     = (unsigned short*)(ws);
    unsigned short* hw     = (unsigned short*)(ws + OFF_HW);
    unsigned short* w1t    = (unsigned short*)(ws + OFF_HW);  // dead before hw written
    int*            cursor = (int*)  (ws + OFF_CUR);
    unsigned int*   ev2    = (unsigned int*)(ws + OFF_EV);

    init_kernel<<<(N_NODES + 255) / 256, 256, 0, stream>>>(cursor, W1, w1t);
    gemm1_scatter_kernel<<<GEMM_BLOCKS + SCAT_BLOCKS, 256, 0, stream>>>(
        x, w1t, xw, dst, src, adj_vals, cursor, ev2);
    spmm1_gemm2_kernel<<<N_NODES / 4, 256, 0, stream>>>(xw, ev2, cursor, b1, W2, hw);
    spmm2_lsm_kernel<<<N_NODES / 4, 256, 0, stream>>>(hw, ev2, cursor, b2, out);
}